// Round 2
// baseline (39.455 us; speedup 1.0000x reference)
//
#include <hip/hip_runtime.h>
#include <math.h>

typedef float f4 __attribute__((ext_vector_type(4)));

#define NBLOCKS 2048
#define NTHREADS 256
// Per block-tile: 256 threads x 3 float4 = 768 f4 = 3072 floats = 1024 samples.
#define TILE_F4 768
// LDS chunk stride in f4 units: 259 => (259 mod 8)==3, which makes the write
// pattern (3*(j%3) + j/3) mod 8 a bijection on every 8 consecutive j
// => conflict-free ds_write_b128; reads are lane-contiguous => conflict-free.
#define CS 259

// Kernel 1: streaming accumulation of the 6 second moments of d = pred - targ.
// Global loads are wave-contiguous (lane i -> base + i), LDS redistributes so
// each thread owns 4 complete samples (12 consecutive floats).
__global__ __launch_bounds__(NTHREADS) void moments_kernel(
    const f4* __restrict__ pred, const f4* __restrict__ targ,
    float* __restrict__ partials, int ntiles)
{
    __shared__ f4 lds[3 * CS];  // 12432 B

    const int t = threadIdx.x;

    // Write/read LDS indices are tile-invariant.
    int widx[3];
#pragma unroll
    for (int k = 0; k < 3; ++k) {
        const int j = k * NTHREADS + t;   // flat f4 index within tile
        widx[k] = (j % 3) * CS + (j / 3); // transposed [chunk][owner] layout
    }
    const int r0 = 0 * CS + t, r1 = 1 * CS + t, r2 = 2 * CS + t;

    float m00 = 0.f, m01 = 0.f, m02 = 0.f, m11 = 0.f, m12 = 0.f, m22 = 0.f;

    for (int T = blockIdx.x; T < ntiles; T += gridDim.x) {
        const long long base = (long long)T * TILE_F4 + t;
        // Perfectly coalesced: each instruction covers 1 KiB contiguous per wave.
        f4 p0 = pred[base], p1 = pred[base + 256], p2 = pred[base + 512];
        f4 q0 = targ[base], q1 = targ[base + 256], q2 = targ[base + 512];

        lds[widx[0]] = p0 - q0;
        lds[widx[1]] = p1 - q1;
        lds[widx[2]] = p2 - q2;
        __syncthreads();

        // Thread t gets flat f4 indices 3t, 3t+1, 3t+2 => floats 12t..12t+11
        // => 4 complete (x,y,z) samples.
        f4 a = lds[r0], b = lds[r1], c = lds[r2];
        __syncthreads();

        float xs[4] = { a.x, a.w, b.z, c.y };
        float ys[4] = { a.y, b.x, b.w, c.z };
        float zs[4] = { a.z, b.y, c.x, c.w };
#pragma unroll
        for (int s = 0; s < 4; ++s) {
            const float x = xs[s], y = ys[s], z = zs[s];
            m00 += x * x; m11 += y * y; m22 += z * z;
            m01 += x * y; m02 += x * z; m12 += y * z;
        }
    }

    // Wave-64 down-reduce
    float acc[6] = { m00, m01, m02, m11, m12, m22 };
#pragma unroll
    for (int off = 32; off > 0; off >>= 1) {
#pragma unroll
        for (int k = 0; k < 6; ++k) acc[k] += __shfl_down(acc[k], off, 64);
    }

    __shared__ float sm[4][6];
    const int wave = t >> 6;
    const int lane = t & 63;
    if (lane == 0) {
#pragma unroll
        for (int k = 0; k < 6; ++k) sm[wave][k] = acc[k];
    }
    __syncthreads();
    if (t == 0) {
#pragma unroll
        for (int k = 0; k < 6; ++k)
            partials[blockIdx.x * 6 + k] = sm[0][k] + sm[1][k] + sm[2][k] + sm[3][k];
    }
}

// Kernel 2: reduce block partials (double), add scalar tail, 3x3 inverse +
// logdet in double, write |logdet + quad| as float.
__global__ __launch_bounds__(NTHREADS) void finalize_kernel(
    const float* __restrict__ partials, const float* __restrict__ sigma,
    const float* __restrict__ pred, const float* __restrict__ targ,
    float* __restrict__ out, int nblocks, int tail_start, int n)
{
    double a[6] = { 0, 0, 0, 0, 0, 0 };
    for (int b = threadIdx.x; b < nblocks; b += blockDim.x) {
#pragma unroll
        for (int k = 0; k < 6; ++k) a[k] += (double)partials[b * 6 + k];
    }
#pragma unroll
    for (int off = 32; off > 0; off >>= 1) {
#pragma unroll
        for (int k = 0; k < 6; ++k) a[k] += __shfl_down(a[k], off, 64);
    }

    __shared__ double sm[4][6];
    const int wave = threadIdx.x >> 6;
    const int lane = threadIdx.x & 63;
    if (lane == 0) {
#pragma unroll
        for (int k = 0; k < 6; ++k) sm[wave][k] = a[k];
    }
    __syncthreads();

    if (threadIdx.x == 0) {
        double M[6];
#pragma unroll
        for (int k = 0; k < 6; ++k) M[k] = sm[0][k] + sm[1][k] + sm[2][k] + sm[3][k];

        // scalar tail (samples not covered by the full tiles)
        for (int i = tail_start; i < n; ++i) {
            double x = (double)pred[3 * i + 0] - (double)targ[3 * i + 0];
            double y = (double)pred[3 * i + 1] - (double)targ[3 * i + 1];
            double z = (double)pred[3 * i + 2] - (double)targ[3 * i + 2];
            M[0] += x * x; M[1] += x * y; M[2] += x * z;
            M[3] += y * y; M[4] += y * z; M[5] += z * z;
        }

        const double invN = 1.0 / (double)n;
#pragma unroll
        for (int k = 0; k < 6; ++k) M[k] *= invN;

        // general 3x3 inverse via adjugate (double)
        double s00 = sigma[0], s01 = sigma[1], s02 = sigma[2];
        double s10 = sigma[3], s11 = sigma[4], s12 = sigma[5];
        double s20 = sigma[6], s21 = sigma[7], s22 = sigma[8];

        double c00 = s11 * s22 - s12 * s21;
        double c01 = s12 * s20 - s10 * s22;
        double c02 = s10 * s21 - s11 * s20;
        double det = s00 * c00 + s01 * c01 + s02 * c02;
        double invdet = 1.0 / det;

        double i00 = (s11 * s22 - s12 * s21) * invdet;
        double i01 = (s02 * s21 - s01 * s22) * invdet;
        double i02 = (s01 * s12 - s02 * s11) * invdet;
        double i10 = (s12 * s20 - s10 * s22) * invdet;
        double i11 = (s00 * s22 - s02 * s20) * invdet;
        double i12 = (s02 * s10 - s00 * s12) * invdet;
        double i20 = (s10 * s21 - s11 * s20) * invdet;
        double i21 = (s01 * s20 - s00 * s21) * invdet;
        double i22 = (s00 * s11 - s01 * s10) * invdet;

        // quad = sum_ij inv_ij * mean(d_i d_j); M = [m00,m01,m02,m11,m12,m22]
        double quad = i00 * M[0] + i11 * M[3] + i22 * M[5]
                    + (i01 + i10) * M[1] + (i02 + i20) * M[2] + (i12 + i21) * M[4];

        double logdet = log(fabs(det));
        out[0] = (float)fabs(logdet + quad);
    }
}

extern "C" void kernel_launch(void* const* d_in, const int* in_sizes, int n_in,
                              void* d_out, int out_size, void* d_ws, size_t ws_size,
                              hipStream_t stream) {
    const float* pred  = (const float*)d_in[0];
    const float* targ  = (const float*)d_in[1];
    const float* sigma = (const float*)d_in[2];
    float* out = (float*)d_out;

    const int n = in_sizes[0] / 3;          // number of samples
    const int nf4 = in_sizes[0] / 4;        // flat float4 count
    const int ntiles = nf4 / TILE_F4;       // full block-tiles
    const int tail_start = (ntiles * TILE_F4 * 4) / 3;  // first sample not covered

    float* partials = (float*)d_ws;         // NBLOCKS * 6 floats

    moments_kernel<<<NBLOCKS, NTHREADS, 0, stream>>>(
        (const f4*)pred, (const f4*)targ, partials, ntiles);
    finalize_kernel<<<1, NTHREADS, 0, stream>>>(
        partials, sigma, pred, targ, out, NBLOCKS, tail_start, n);
}